// Round 12
// baseline (64.568 us; speedup 1.0000x reference)
//
#include <hip/hip_runtime.h>

#define N_NODES 10000
#define N_EDGES 160000
#define IN_DIM 512
#define HID 128
#define OUT_DIM 64
#define CAP 64                      // ELL capacity; P(Poisson(16) > 64) ~ 3e-22

typedef __attribute__((ext_vector_type(8))) short bf16x8;
typedef __attribute__((ext_vector_type(4))) float f32x4;

__device__ inline ushort f2b(float f) {
    unsigned u = __float_as_uint(f);
    u += 0x7fff + ((u >> 16) & 1);   // round-to-nearest-even
    return (ushort)(u >> 16);
}
__device__ inline uint pack2(float a, float b) {
    return (uint)f2b(a) | ((uint)f2b(b) << 16);
}
__device__ inline float blo(uint u) { return __uint_as_float(u << 16); }
__device__ inline float bhi(uint u) { return __uint_as_float(u & 0xffff0000u); }

// ---------------------------------------------------------------------------
// zero deg[] (int4 chunks) — only prep needed now (weights staged from f32)
// ---------------------------------------------------------------------------
__global__ void zero_deg(int* __restrict__ deg) {
    int i = blockIdx.x * blockDim.x + threadIdx.x;
    if (i < N_NODES / 4) ((int4*)deg)[i] = make_int4(0, 0, 0, 0);
}

// ---------------------------------------------------------------------------
// Layer-1 GEMM body: C[M,256] = A[M,512] * [W1l;W1r][256,512]^T.
// BM=32, BN=128, BK=64; 4 waves: wave w -> rows (w&1)*16, cols (w>>1)*64
// (CF=4). A f32->bf16 staged; B panel staged f32->bf16 (bx=0 -> W1l, 1 -> W1r).
// XOR swizzle chunk' = chunk^(row&7) (verified R3-R11).
// Cols < 128 -> XL (bf16), else XR (bf16).
// ---------------------------------------------------------------------------
__device__ __forceinline__ void gemm1_body(int bx, int by,
    const float* __restrict__ A, const float* __restrict__ bpanel,
    ushort* __restrict__ XL, ushort* __restrict__ XR) {
    constexpr int CF = 4;
    __shared__ __align__(16) ushort Asm[32 * 64];
    __shared__ __align__(16) ushort Bsm[128 * 64];

    const int t    = threadIdx.x;
    const int lane = t & 63;
    const int w    = t >> 6;
    const int wr   = w & 1;
    const int wc   = w >> 1;
    const int m0   = by * 32;
    const int n0   = bx * 128;
    const int kch  = lane >> 4;
    const int lrow = lane & 15;

    f32x4 acc[CF] = {};

    for (int k0 = 0; k0 < IN_DIM; k0 += 64) {
        {   // stage A (32 x 64), one 16B chunk per thread, f32 -> bf16
            int row = t >> 3, c = t & 7;
            int m = m0 + row;
            uint4 o = make_uint4(0u, 0u, 0u, 0u);
            if (m < N_NODES) {
                const float* p = A + (size_t)m * IN_DIM + k0 + c * 8;
                float4 v0 = reinterpret_cast<const float4*>(p)[0];
                float4 v1 = reinterpret_cast<const float4*>(p)[1];
                o.x = pack2(v0.x, v0.y); o.y = pack2(v0.z, v0.w);
                o.z = pack2(v1.x, v1.y); o.w = pack2(v1.z, v1.w);
            }
            *reinterpret_cast<uint4*>(&Asm[row * 64 + ((c ^ (row & 7)) << 3)]) = o;
        }
        #pragma unroll
        for (int ch = t; ch < 128 * 8; ch += 256) {  // stage B (128 x 64), f32 -> bf16
            int row = ch >> 3, c = ch & 7;
            const float* p = bpanel + (size_t)row * IN_DIM + k0 + c * 8;
            float4 v0 = reinterpret_cast<const float4*>(p)[0];
            float4 v1 = reinterpret_cast<const float4*>(p)[1];
            uint4 o;
            o.x = pack2(v0.x, v0.y); o.y = pack2(v0.z, v0.w);
            o.z = pack2(v1.x, v1.y); o.w = pack2(v1.z, v1.w);
            *reinterpret_cast<uint4*>(&Bsm[row * 64 + ((c ^ (row & 7)) << 3)]) = o;
        }
        __syncthreads();

        const int arow = wr * 16 + lrow;
        #pragma unroll
        for (int h = 0; h < 2; ++h) {
            int c = h * 4 + kch;
            bf16x8 afr = *reinterpret_cast<const bf16x8*>(&Asm[arow * 64 + ((c ^ (arow & 7)) << 3)]);
            #pragma unroll
            for (int cf = 0; cf < CF; ++cf) {
                int brow = wc * 64 + cf * 16 + lrow;
                bf16x8 bfr = *reinterpret_cast<const bf16x8*>(&Bsm[brow * 64 + ((c ^ (brow & 7)) << 3)]);
                acc[cf] = __builtin_amdgcn_mfma_f32_16x16x32_bf16(afr, bfr, acc[cf], 0, 0, 0);
            }
        }
        __syncthreads();
    }

    // epilogue: col = lane&15 (+frag*16), row = (lane>>4)*4 + j  [m89 layout]
    #pragma unroll
    for (int cf = 0; cf < CF; ++cf) {
        int col = n0 + wc * 64 + cf * 16 + lrow;
        #pragma unroll
        for (int j = 0; j < 4; ++j) {
            int row = m0 + wr * 16 + kch * 4 + j;
            if (row >= N_NODES) continue;
            if (col < HID) XL[(size_t)row * HID + col] = f2b(acc[cf][j]);
            else           XR[(size_t)row * HID + (col - HID)] = f2b(acc[cf][j]);
        }
    }
}

// ---------------------------------------------------------------------------
// FAT: blocks [0,626) = layer-1 GEMM (BN=128; col-major: 313 blocks share a
// W-panel); blocks [626,1251) = ELL bucket fill (independent work).
// ---------------------------------------------------------------------------
#define ROWB ((N_NODES + 31) / 32)          // 313
#define G1_BLOCKS (2 * ROWB)                // 626
#define FILL_BLOCKS ((N_EDGES + 255) / 256) // 625

__global__ __launch_bounds__(256) void fat_gemm1_fill(
    const float* __restrict__ x,
    const float* __restrict__ w1l, const float* __restrict__ w1r,
    ushort* __restrict__ XL, ushort* __restrict__ XR,
    const int* __restrict__ src, const int* __restrict__ dst,
    int* __restrict__ deg, int* __restrict__ bell) {
    int b = blockIdx.x;
    if (b < G1_BLOCKS) {
        int bx = b / ROWB, by = b % ROWB;
        gemm1_body(bx, by, x, (bx == 0) ? w1l : w1r, XL, XR);
    } else {
        int e = (b - G1_BLOCKS) * 256 + threadIdx.x;
        if (e < N_EDGES) {
            int d = dst[e];
            int pos = atomicAdd(&deg[d], 1);
            if (pos < CAP) bell[d * CAP + pos] = src[e];
        }
    }
}

// ---------------------------------------------------------------------------
// Fused gather1 + layer-2 GEMM at FULL gather parallelism.
// 625 blocks x 1024 threads (16 waves). 16 nodes/block, ONE node per wave.
// Phase a: stage [W2l;W2r] (f32 -> bf16, swizzled) into LDS Bs (R10-verified).
// Phase b: wave w gathers node base+w (R8-verified body), h -> swizzled Ah.
// Phase c: waves 0..7: col-frag w, 4 MFMA over K=128; epilogue HL|HR (bf16).
// ---------------------------------------------------------------------------
__global__ __launch_bounds__(1024) void gather1_gemm2(
    const ushort* __restrict__ XL, const ushort* __restrict__ XR,
    const float* __restrict__ b1, const int* __restrict__ deg,
    const int* __restrict__ bell,
    const float* __restrict__ w2l, const float* __restrict__ w2r,
    ushort* __restrict__ HL, ushort* __restrict__ HR) {
    __shared__ __align__(16) ushort Ah[16 * 128];    // 4 KB  (h tile, bf16)
    __shared__ __align__(16) ushort Bs[128 * 128];   // 32 KB ([W2l;W2r], bf16)

    const int t    = threadIdx.x;
    const int lane = t & 63;
    const int w    = t >> 6;          // 0..15
    const int base = blockIdx.x * 16;

    // phase a: stage B = [W2l;W2r] (128 rows x 128 K), 2 chunks per thread
    #pragma unroll
    for (int ch = t; ch < 128 * 16; ch += 1024) {
        int row = ch >> 4, c = ch & 15;
        const float* p = ((row < 64) ? (w2l + (size_t)row * HID)
                                     : (w2r + (size_t)(row - 64) * HID)) + c * 8;
        float4 v0 = reinterpret_cast<const float4*>(p)[0];
        float4 v1 = reinterpret_cast<const float4*>(p)[1];
        uint4 o;
        o.x = pack2(v0.x, v0.y); o.y = pack2(v0.z, v0.w);
        o.z = pack2(v1.x, v1.y); o.w = pack2(v1.z, v1.w);
        *reinterpret_cast<uint4*>(&Bs[row * 128 + ((c ^ (row & 7)) << 3)]) = o;
    }

    // phase b: wave w gathers node base+w; lane owns features 2*lane, 2*lane+1
    {
        int n = base + w;
        float v0 = 0.f, v1 = 0.f;
        if (n < N_NODES) {
            int d = min(deg[n], CAP);
            const int* lst = bell + (size_t)n * CAP;
            float a0 = 0.f, a1 = 0.f;
            int i = 0;
            for (; i + 4 <= d; i += 4) {
                int s0 = lst[i], s1 = lst[i + 1], s2 = lst[i + 2], s3 = lst[i + 3];
                uint u0 = *(const uint*)(XL + (size_t)s0 * 128 + lane * 2);
                uint u1 = *(const uint*)(XL + (size_t)s1 * 128 + lane * 2);
                uint u2 = *(const uint*)(XL + (size_t)s2 * 128 + lane * 2);
                uint u3 = *(const uint*)(XL + (size_t)s3 * 128 + lane * 2);
                a0 += blo(u0) + blo(u1) + blo(u2) + blo(u3);
                a1 += bhi(u0) + bhi(u1) + bhi(u2) + bhi(u3);
            }
            for (; i < d; ++i) {
                uint u = *(const uint*)(XL + (size_t)lst[i] * 128 + lane * 2);
                a0 += blo(u); a1 += bhi(u);
            }
            float inv = (d > 0) ? (1.0f / (float)d) : 0.0f;
            uint ux = *(const uint*)(XR + (size_t)n * 128 + lane * 2);
            v0 = fmaxf(a0 * inv + blo(ux) + b1[lane * 2], 0.f);
            v1 = fmaxf(a1 * inv + bhi(ux) + b1[lane * 2 + 1], 0.f);
        }
        int c = lane >> 2;   // 16B chunk within the 128-feature row
        *(uint*)&Ah[w * 128 + ((c ^ (w & 7)) << 3) + (lane & 3) * 2] = pack2(v0, v1);
    }
    __syncthreads();

    // phase c: waves 0..7: wave w -> cols w*16..w*16+15, rows = 16 nodes, K=128
    if (w < 8) {
        const int kch = lane >> 4, lrow = lane & 15;
        const int arow = lrow;
        f32x4 acc = {};
        #pragma unroll
        for (int ks = 0; ks < 4; ++ks) {
            int c = ks * 4 + kch;
            bf16x8 afr = *reinterpret_cast<const bf16x8*>(&Ah[arow * 128 + ((c ^ (arow & 7)) << 3)]);
            int brow = w * 16 + lrow;
            bf16x8 bfr = *reinterpret_cast<const bf16x8*>(&Bs[brow * 128 + ((c ^ (brow & 7)) << 3)]);
            acc = __builtin_amdgcn_mfma_f32_16x16x32_bf16(afr, bfr, acc, 0, 0, 0);
        }
        // epilogue: col = lane&15 (+w*16), row = (lane>>4)*4 + j  [m89 layout]
        int col = w * 16 + lrow;
        #pragma unroll
        for (int j = 0; j < 4; ++j) {
            int row = base + kch * 4 + j;
            if (row >= N_NODES) continue;
            if (col < OUT_DIM) HL[(size_t)row * OUT_DIM + col] = f2b(acc[j]);
            else               HR[(size_t)row * OUT_DIM + (col - OUT_DIM)] = f2b(acc[j]);
        }
    }
}

// ---------------------------------------------------------------------------
// Final gather (R8-verified): out = mean_agg(HL) + HR + b2 (f32 out).
// ---------------------------------------------------------------------------
__global__ __launch_bounds__(256) void gather2(
    const ushort* __restrict__ V, const ushort* __restrict__ xr,
    const float* __restrict__ b, const int* __restrict__ deg,
    const int* __restrict__ bell, float* __restrict__ out) {
    int wave = threadIdx.x >> 6;
    int lane = threadIdx.x & 63;
    int n = blockIdx.x * 4 + wave;
    if (n >= N_NODES) return;

    int d = min(deg[n], CAP);
    const int* lst = bell + (size_t)n * CAP;

    float a0 = 0.f;
    int i = 0;
    for (; i + 4 <= d; i += 4) {
        int s0 = lst[i], s1 = lst[i + 1], s2 = lst[i + 2], s3 = lst[i + 3];
        a0 += blo((uint)V[(size_t)s0 * 64 + lane]) + blo((uint)V[(size_t)s1 * 64 + lane])
            + blo((uint)V[(size_t)s2 * 64 + lane]) + blo((uint)V[(size_t)s3 * 64 + lane]);
    }
    for (; i < d; ++i) a0 += blo((uint)V[(size_t)lst[i] * 64 + lane]);

    float inv = (d > 0) ? (1.0f / (float)d) : 0.0f;
    out[(size_t)n * 64 + lane] = a0 * inv + blo((uint)xr[(size_t)n * 64 + lane]) + b[lane];
}

// ---------------------------------------------------------------------------
extern "C" void kernel_launch(void* const* d_in, const int* in_sizes, int n_in,
                              void* d_out, int out_size, void* d_ws, size_t ws_size,
                              hipStream_t stream) {
    const float* x   = (const float*)d_in[0];
    const int*   ei  = (const int*)d_in[1];
    const int*   src = ei;
    const int*   dst = ei + N_EDGES;
    const float* W1l = (const float*)d_in[2];
    const float* W1r = (const float*)d_in[3];
    const float* b1  = (const float*)d_in[4];
    const float* W2l = (const float*)d_in[5];
    const float* W2r = (const float*)d_in[6];
    const float* b2  = (const float*)d_in[7];
    float*       out = (float*)d_out;

    // Workspace layout (16B-aligned segments)
    int* deg  = (int*)d_ws;                                 // N
    int* bell = deg + N_NODES;                              // N*CAP
    ushort* XL = (ushort*)(bell + (size_t)N_NODES * CAP);   // N*128 bf16
    ushort* XR = XL + (size_t)N_NODES * HID;                // N*128 bf16
    ushort* HL = XR + (size_t)N_NODES * HID;                // N*64 bf16
    ushort* HR = HL + (size_t)N_NODES * OUT_DIM;            // N*64 bf16

    // 1) zero deg
    zero_deg<<<(N_NODES / 4 + 255) / 256, 256, 0, stream>>>(deg);

    // 2) layer-1 GEMM (626 blocks, f32 weights) || ELL fill (625 blocks)
    fat_gemm1_fill<<<G1_BLOCKS + FILL_BLOCKS, 256, 0, stream>>>(
        x, W1l, W1r, XL, XR, src, dst, deg, bell);

    // 3) h = relu(mean_agg(XL) + XR + b1) fused with [HL|HR] = h @ [W2l;W2r]^T
    //    (full gather parallelism: 1 node per wave)
    gather1_gemm2<<<(N_NODES + 15) / 16, 1024, 0, stream>>>(
        XL, XR, b1, deg, bell, W2l, W2r, HL, HR);

    // 4) out = mean_agg(HL) + HR + b2
    gather2<<<(N_NODES + 3) / 4, 256, 0, stream>>>(HL, HR, b2, deg, bell, out);
}

// Round 13
// 62.848 us; speedup vs baseline: 1.0274x; 1.0274x over previous
//
#include <hip/hip_runtime.h>

#define N_NODES 10000
#define N_EDGES 160000
#define IN_DIM 512
#define HID 128
#define OUT_DIM 64
#define CAP 64                      // ELL capacity; P(Poisson(16) > 64) ~ 3e-22

typedef __attribute__((ext_vector_type(8))) short bf16x8;
typedef __attribute__((ext_vector_type(4))) float f32x4;

// Native bf16 conversion (RNE): compiler emits v_cvt_pk_bf16_f32 for pairs.
__device__ inline ushort f2b(float f) {
    __bf16 h = (__bf16)f;
    return __builtin_bit_cast(ushort, h);
}
__device__ inline uint pack2(float a, float b) {
    return (uint)f2b(a) | ((uint)f2b(b) << 16);
}
__device__ inline float blo(uint u) { return __uint_as_float(u << 16); }
__device__ inline float bhi(uint u) { return __uint_as_float(u & 0xffff0000u); }

// ---------------------------------------------------------------------------
// prep: zero deg[] (int4) and convert W1/W2 -> bf16 (float4 chunks)
// ---------------------------------------------------------------------------
#define ZCH (N_NODES / 4)             // 2500 int4 chunks (deg)
#define W1CH (HID * IN_DIM / 4)       // 16384 float4 chunks per W1 matrix
#define W2CH (OUT_DIM * HID / 4)      // 2048 per W2 matrix
#define PREP_TOT (ZCH + 2 * W1CH + 2 * W2CH)

__global__ void prep(int* __restrict__ deg,
                     const float* __restrict__ w1l, const float* __restrict__ w1r,
                     const float* __restrict__ w2l, const float* __restrict__ w2r,
                     ushort* __restrict__ wc1, ushort* __restrict__ wc2) {
    int i = blockIdx.x * blockDim.x + threadIdx.x;
    if (i < ZCH) { ((int4*)deg)[i] = make_int4(0, 0, 0, 0); return; }
    i -= ZCH;
    const float* src; ushort* dst;
    if      (i < W1CH)            { src = w1l + (size_t)i * 4;             dst = wc1 + (size_t)i * 4; }
    else if (i < 2 * W1CH)        { int j = i - W1CH;          src = w1r + (size_t)j * 4; dst = wc1 + HID * IN_DIM + (size_t)j * 4; }
    else if (i < 2 * W1CH + W2CH) { int j = i - 2 * W1CH;      src = w2l + (size_t)j * 4; dst = wc2 + (size_t)j * 4; }
    else if (i < PREP_TOT - ZCH)  { int j = i - 2 * W1CH - W2CH; src = w2r + (size_t)j * 4; dst = wc2 + OUT_DIM * HID + (size_t)j * 4; }
    else return;
    float4 v = *reinterpret_cast<const float4*>(src);
    ushort4 o = make_ushort4(f2b(v.x), f2b(v.y), f2b(v.z), f2b(v.w));
    *reinterpret_cast<ushort4*>(dst) = o;
}

// ---------------------------------------------------------------------------
// MFMA GEMM body (R8-verified core): C[M,NT] = A[M,K]*B[NT,K]^T.
// BM=32, BK=64, BN templated (64 or 128). 4 waves: wave w -> rows (w&1)*16,
// cols (w>>1)*(BN/2), CF=BN/32 fragments. XOR swizzle chunk'=chunk^(row&7).
// BOTH outputs bf16: cols < HALF -> C0, else C1.
// ---------------------------------------------------------------------------
template <typename AT, int BN, int K, int NT, int HALF>
__device__ __forceinline__ void gemm_body(int bx, int by,
    const AT* __restrict__ A, const ushort* __restrict__ B,
    ushort* __restrict__ C0, ushort* __restrict__ C1, int M) {
    constexpr int CF = BN / 32;
    __shared__ __align__(16) ushort Asm[32 * 64];
    __shared__ __align__(16) ushort Bsm[BN * 64];

    const int t    = threadIdx.x;
    const int lane = t & 63;
    const int w    = t >> 6;
    const int wr   = w & 1;
    const int wc   = w >> 1;
    const int m0   = by * 32;
    const int n0   = bx * BN;
    const int kch  = lane >> 4;
    const int lrow = lane & 15;

    f32x4 acc[CF] = {};

    for (int k0 = 0; k0 < K; k0 += 64) {
        {   // stage A (32 x 64) — one 16B chunk per thread
            int row = t >> 3, c = t & 7;
            int m = m0 + row;
            uint4 o = make_uint4(0u, 0u, 0u, 0u);
            if (m < M) {
                if constexpr (sizeof(AT) == 4) {
                    const float* p = (const float*)A + (size_t)m * K + k0 + c * 8;
                    float4 v0 = reinterpret_cast<const float4*>(p)[0];
                    float4 v1 = reinterpret_cast<const float4*>(p)[1];
                    o.x = pack2(v0.x, v0.y); o.y = pack2(v0.z, v0.w);
                    o.z = pack2(v1.x, v1.y); o.w = pack2(v1.z, v1.w);
                } else {
                    o = *reinterpret_cast<const uint4*>((const ushort*)A + (size_t)m * K + k0 + c * 8);
                }
            }
            *reinterpret_cast<uint4*>(&Asm[row * 64 + ((c ^ (row & 7)) << 3)]) = o;
        }
        #pragma unroll
        for (int ch = t; ch < BN * 8; ch += 256) {   // stage B (BN x 64), bf16
            int row = ch >> 3, c = ch & 7;
            uint4 o = *reinterpret_cast<const uint4*>(&B[(size_t)(n0 + row) * K + k0 + c * 8]);
            *reinterpret_cast<uint4*>(&Bsm[row * 64 + ((c ^ (row & 7)) << 3)]) = o;
        }
        __syncthreads();

        const int arow = wr * 16 + lrow;
        #pragma unroll
        for (int h = 0; h < 2; ++h) {
            int c = h * 4 + kch;
            bf16x8 afr = *reinterpret_cast<const bf16x8*>(&Asm[arow * 64 + ((c ^ (arow & 7)) << 3)]);
            #pragma unroll
            for (int cf = 0; cf < CF; ++cf) {
                int brow = wc * (BN / 2) + cf * 16 + lrow;
                bf16x8 bfr = *reinterpret_cast<const bf16x8*>(&Bsm[brow * 64 + ((c ^ (brow & 7)) << 3)]);
                acc[cf] = __builtin_amdgcn_mfma_f32_16x16x32_bf16(afr, bfr, acc[cf], 0, 0, 0);
            }
        }
        __syncthreads();
    }

    // epilogue: col = lane&15 (+frag*16), row = (lane>>4)*4 + j  [m89 layout]
    #pragma unroll
    for (int cf = 0; cf < CF; ++cf) {
        int col = n0 + wc * (BN / 2) + cf * 16 + lrow;
        #pragma unroll
        for (int j = 0; j < 4; ++j) {
            int row = m0 + wr * 16 + kch * 4 + j;
            if (row >= M) continue;
            if (col < HALF) C0[(size_t)row * HALF + col] = f2b(acc[cf][j]);
            else            C1[(size_t)row * (NT - HALF) + (col - HALF)] = f2b(acc[cf][j]);
        }
    }
}

// ---------------------------------------------------------------------------
// FAT: blocks [0,626) = layer-1 GEMM (BN=128; col-major: 313 blocks share a
// B-panel); blocks [626,1251) = ELL bucket fill (independent work).
// ---------------------------------------------------------------------------
#define ROWB ((N_NODES + 31) / 32)          // 313
#define G1_BLOCKS (2 * ROWB)                // 626 (NT=256 / BN=128)
#define FILL_BLOCKS ((N_EDGES + 255) / 256) // 625

__global__ __launch_bounds__(256) void fat_gemm1_fill(
    const float* __restrict__ x, const ushort* __restrict__ wc1,
    ushort* __restrict__ XL, ushort* __restrict__ XR,
    const int* __restrict__ src, const int* __restrict__ dst,
    int* __restrict__ deg, int* __restrict__ bell) {
    int b = blockIdx.x;
    if (b < G1_BLOCKS) {
        gemm_body<float, 128, IN_DIM, 256, HID>(b / ROWB, b % ROWB, x, wc1, XL, XR, N_NODES);
    } else {
        int e = (b - G1_BLOCKS) * 256 + threadIdx.x;
        if (e < N_EDGES) {
            int d = dst[e];
            int pos = atomicAdd(&deg[d], 1);
            if (pos < CAP) bell[d * CAP + pos] = src[e];
        }
    }
}

// Layer-2 GEMM: NT=128, BN=64 (626 blocks)
__global__ __launch_bounds__(256) void gemm2_kernel(
    const ushort* __restrict__ hb, const ushort* __restrict__ wc2,
    ushort* __restrict__ HL, ushort* __restrict__ HR) {
    gemm_body<ushort, 64, HID, 128, OUT_DIM>(blockIdx.x / ROWB, blockIdx.x % ROWB,
                                             hb, wc2, HL, HR, N_NODES);
}

// ---------------------------------------------------------------------------
// Gather 1 (R8-verified body): h = relu(mean_agg(XL) + XR + b1) -> bf16 hb.
// One wave per node; XR bf16.
// ---------------------------------------------------------------------------
__global__ __launch_bounds__(256) void gather1(
    const ushort* __restrict__ V, const ushort* __restrict__ xr,
    const float* __restrict__ b, const int* __restrict__ deg,
    const int* __restrict__ bell, ushort* __restrict__ out) {
    int wave = threadIdx.x >> 6;
    int lane = threadIdx.x & 63;
    int n = blockIdx.x * 4 + wave;
    if (n >= N_NODES) return;

    int d = min(deg[n], CAP);
    const int* lst = bell + (size_t)n * CAP;

    float a0 = 0.f, a1 = 0.f;
    int i = 0;
    for (; i + 4 <= d; i += 4) {
        int s0 = lst[i], s1 = lst[i + 1], s2 = lst[i + 2], s3 = lst[i + 3];
        uint u0 = *(const uint*)(V + (size_t)s0 * 128 + lane * 2);
        uint u1 = *(const uint*)(V + (size_t)s1 * 128 + lane * 2);
        uint u2 = *(const uint*)(V + (size_t)s2 * 128 + lane * 2);
        uint u3 = *(const uint*)(V + (size_t)s3 * 128 + lane * 2);
        a0 += blo(u0) + blo(u1) + blo(u2) + blo(u3);
        a1 += bhi(u0) + bhi(u1) + bhi(u2) + bhi(u3);
    }
    for (; i < d; ++i) {
        uint u = *(const uint*)(V + (size_t)lst[i] * 128 + lane * 2);
        a0 += blo(u); a1 += bhi(u);
    }

    float inv = (d > 0) ? (1.0f / (float)d) : 0.0f;
    uint ux = *(const uint*)(xr + (size_t)n * 128 + lane * 2);
    float v0 = fmaxf(a0 * inv + blo(ux) + b[lane * 2], 0.f);
    float v1 = fmaxf(a1 * inv + bhi(ux) + b[lane * 2 + 1], 0.f);
    *(uint*)(out + (size_t)n * 128 + lane * 2) = pack2(v0, v1);
}

// ---------------------------------------------------------------------------
// Gather 2 (R8-verified body): out = mean_agg(HL) + HR + b2 (f32 out).
// HR bf16.
// ---------------------------------------------------------------------------
__global__ __launch_bounds__(256) void gather2(
    const ushort* __restrict__ V, const ushort* __restrict__ xr,
    const float* __restrict__ b, const int* __restrict__ deg,
    const int* __restrict__ bell, float* __restrict__ out) {
    int wave = threadIdx.x >> 6;
    int lane = threadIdx.x & 63;
    int n = blockIdx.x * 4 + wave;
    if (n >= N_NODES) return;

    int d = min(deg[n], CAP);
    const int* lst = bell + (size_t)n * CAP;

    float a0 = 0.f;
    int i = 0;
    for (; i + 4 <= d; i += 4) {
        int s0 = lst[i], s1 = lst[i + 1], s2 = lst[i + 2], s3 = lst[i + 3];
        a0 += blo((uint)V[(size_t)s0 * 64 + lane]) + blo((uint)V[(size_t)s1 * 64 + lane])
            + blo((uint)V[(size_t)s2 * 64 + lane]) + blo((uint)V[(size_t)s3 * 64 + lane]);
    }
    for (; i < d; ++i) a0 += blo((uint)V[(size_t)lst[i] * 64 + lane]);

    float inv = (d > 0) ? (1.0f / (float)d) : 0.0f;
    out[(size_t)n * 64 + lane] = a0 * inv + blo((uint)xr[(size_t)n * 64 + lane]) + b[lane];
}

// ---------------------------------------------------------------------------
extern "C" void kernel_launch(void* const* d_in, const int* in_sizes, int n_in,
                              void* d_out, int out_size, void* d_ws, size_t ws_size,
                              hipStream_t stream) {
    const float* x   = (const float*)d_in[0];
    const int*   ei  = (const int*)d_in[1];
    const int*   src = ei;
    const int*   dst = ei + N_EDGES;
    const float* W1l = (const float*)d_in[2];
    const float* W1r = (const float*)d_in[3];
    const float* b1  = (const float*)d_in[4];
    const float* W2l = (const float*)d_in[5];
    const float* W2r = (const float*)d_in[6];
    const float* b2  = (const float*)d_in[7];
    float*       out = (float*)d_out;

    // Workspace layout (16B-aligned segments)
    int* deg  = (int*)d_ws;                                 // N
    int* bell = deg + N_NODES;                              // N*CAP
    ushort* wc1 = (ushort*)(bell + (size_t)N_NODES * CAP);  // 2*128*512 bf16
    ushort* wc2 = wc1 + (size_t)2 * HID * IN_DIM;           // 2*64*128 bf16
    ushort* XL  = wc2 + (size_t)2 * OUT_DIM * HID;          // N*128 bf16
    ushort* XR  = XL + (size_t)N_NODES * HID;               // N*128 bf16
    ushort* hb  = XR + (size_t)N_NODES * HID;               // N*128 bf16
    ushort* HL  = hb + (size_t)N_NODES * HID;               // N*64 bf16
    ushort* HR  = HL + (size_t)N_NODES * OUT_DIM;           // N*64 bf16

    // 1) zero deg, convert weights -> bf16
    prep<<<(PREP_TOT + 255) / 256, 256, 0, stream>>>(deg, W1l, W1r, W2l, W2r, wc1, wc2);

    // 2) layer-1 GEMM (626 blocks, BN=128) || ELL fill (625 blocks)
    fat_gemm1_fill<<<G1_BLOCKS + FILL_BLOCKS, 256, 0, stream>>>(
        x, wc1, XL, XR, src, dst, deg, bell);

    // 3) h = relu(mean_agg(XL) + XR + b1) -> bf16 hb
    gather1<<<(N_NODES + 3) / 4, 256, 0, stream>>>(XL, XR, b1, deg, bell, hb);

    // 4) [HL | HR] = h @ [W2l;W2r]^T
    gemm2_kernel<<<2 * ROWB, 256, 0, stream>>>(hb, wc2, HL, HR);

    // 5) out = mean_agg(HL) + HR + b2
    gather2<<<(N_NODES + 3) / 4, 256, 0, stream>>>(HL, HR, b2, deg, bell, out);
}